// Round 3
// baseline (64.894 us; speedup 1.0000x reference)
//
#include <hip/hip_runtime.h>

// TimeNormalization: EMA scan over time + normalization.
//   s_t = 0.1*[x, x^2] + 0.9*s_{t-1}   (per (b,f), scan over t)
//   x_norm = (x - m) / sqrt(v - m^2 + 1e-3)
// Outputs concatenated: x_norm [B,T,F] then final_state [2,B,F].
//
// Chunked scan: 0.9^128 ~ 1.4e-6 -> KH=128 halo warmup per chunk (chunk 0
// uses exact init state). R2 evidence: doubling waves changed nothing at
// 2.8 TB/s with all pipes <35% -> limited by bytes-per-VMEM-instruction
// (4 B/lane). This version: float4 per thread (16 B/lane, 1 KB/wave-instr),
// matching the pattern that achieves the 6.3 TB/s copy ceiling.

namespace {
constexpr int Bc = 16, Tc = 4096, Fc = 512;
constexpr int CL = 128;          // chunk length
constexpr int KH = 128;          // halo (0.9^128 ~ 1.4e-6; accuracy-critical)
constexpr int NCHUNK = Tc / CL;  // 32
constexpr int F4 = Fc / 4;       // 128 float4 columns
constexpr float ALPHA = 0.1f;
constexpr float OMA = 0.9f;
constexpr float EPS = 1e-3f;
typedef float v4 __attribute__((ext_vector_type(4)));
}

__global__ __launch_bounds__(128) void tn_kernel(const v4* __restrict__ x4,
                                                 const v4* __restrict__ st4,
                                                 v4* __restrict__ out4) {
    const int chunk = blockIdx.x & (NCHUNK - 1);
    const int b = blockIdx.x >> 5;         // NCHUNK = 32
    const int f4 = threadIdx.x;            // 0..127, coalesced float4 columns
    const int t0 = chunk * CL;

    const size_t base = ((size_t)b * Tc + t0) * F4 + f4;
    const v4* xp = x4 + base;

    v4 s_m, s_v;
    if (chunk == 0) {
        // exact initial state: state[0,b,:] (mean), state[1,b,:] (mean-square)
        s_m = st4[(size_t)b * F4 + f4];
        s_v = st4[(size_t)(Bc + b) * F4 + f4];
    } else {
        s_m = (v4)0.f;
        s_v = (v4)0.f;
        const v4* wp = xp - (size_t)KH * F4;
#pragma unroll 8
        for (int i = 0; i < KH; ++i) {
            v4 xv = wp[(size_t)i * F4];
            v4 px = ALPHA * xv;
            s_m = OMA * s_m + px;          // 4 independent fma chains
            s_v = OMA * s_v + px * xv;
        }
    }

    v4* op = out4 + base;
#pragma unroll 8
    for (int i = 0; i < CL; ++i) {
        v4 xv = xp[(size_t)i * F4];
        v4 px = ALPHA * xv;
        s_m = OMA * s_m + px;
        s_v = OMA * s_v + px * xv;
        v4 var = s_v - s_m * s_m + (v4)EPS;
        v4 r;
#pragma unroll
        for (int c = 0; c < 4; ++c) r[c] = (xv[c] - s_m[c]) * rsqrtf(var[c]);
        __builtin_nontemporal_store(r, &op[(size_t)i * F4]);  // write-once stream
    }

    if (chunk == NCHUNK - 1) {
        // final_state [2,B,F] appended after x_norm
        const size_t so = (size_t)Bc * Tc * F4;
        out4[so + (size_t)b * F4 + f4] = s_m;
        out4[so + (size_t)(Bc + b) * F4 + f4] = s_v;
    }
}

extern "C" void kernel_launch(void* const* d_in, const int* in_sizes, int n_in,
                              void* d_out, int out_size, void* d_ws, size_t ws_size,
                              hipStream_t stream) {
    const v4* x = (const v4*)d_in[0];       // [B,T,F] f32
    const v4* st = (const v4*)d_in[1];      // [2,B,F] f32
    v4* out = (v4*)d_out;                   // x_norm + final_state

    dim3 grid(Bc * NCHUNK);                 // 512
    dim3 block(128);                        // F/4 lanes
    tn_kernel<<<grid, block, 0, stream>>>(x, st, out);
}